// Round 1
// baseline (377.508 us; speedup 1.0000x reference)
//
#include <hip/hip_runtime.h>
#include <hip/hip_bf16.h>

#define DIMC 256
#define NB 4
#define NS 4096
#define KT 64               // keys per tile in attention
#define NTILES (NS / KT)

typedef __attribute__((ext_vector_type(4))) float f32x4;
typedef __attribute__((ext_vector_type(8))) short bf16x8;

__device__ __forceinline__ ushort f2bf(float f) {
  __hip_bfloat16 h = __float2bfloat16(f);
  return *reinterpret_cast<ushort*>(&h);
}

// ---------------- QV projection ----------------
// qb  = (x @ Wq^T + bq) * (1/16)   row-major [B*S][256] bf16   (pre-scaled)
// vb  =  x @ Wv^T + bv             row-major [B*S][256] bf16
// vtb =  v transposed per batch    [B][256][S] bf16
__global__ __launch_bounds__(256) void qv_proj_kernel(
    const float* __restrict__ x, const float* __restrict__ W,
    const float* __restrict__ bias,
    ushort* __restrict__ qb, ushort* __restrict__ vb, ushort* __restrict__ vtb)
{
  const int tid = threadIdx.x;
  const int r0 = blockIdx.x << 4;     // 16 rows of (b*S+s) per block
  __shared__ float xs[16][260];
  #pragma unroll
  for (int i = 0; i < 16; ++i)
    xs[i][tid] = x[(size_t)(r0 + i) * DIMC + tid];
  __syncthreads();

  const float4* wq = (const float4*)(W + (size_t)tid * DIMC);          // W row tid  (q)
  const float4* wv = (const float4*)(W + (size_t)(512 + tid) * DIMC);  // W row 512+tid (v)
  float accq[16], accv[16];
  #pragma unroll
  for (int r = 0; r < 16; ++r) { accq[r] = 0.f; accv[r] = 0.f; }
  for (int j4 = 0; j4 < 64; ++j4) {
    float4 a = wq[j4];
    float4 c = wv[j4];
    #pragma unroll
    for (int r = 0; r < 16; ++r) {
      float4 xv = *(const float4*)&xs[r][j4 * 4];
      accq[r] = fmaf(xv.x, a.x, fmaf(xv.y, a.y, fmaf(xv.z, a.z, fmaf(xv.w, a.w, accq[r]))));
      accv[r] = fmaf(xv.x, c.x, fmaf(xv.y, c.y, fmaf(xv.z, c.z, fmaf(xv.w, c.w, accv[r]))));
    }
  }
  const float bq = bias[tid];
  const float bv = bias[512 + tid];
  ushort uv[16];
  #pragma unroll
  for (int r = 0; r < 16; ++r) {
    qb[(size_t)(r0 + r) * DIMC + tid] = f2bf((accq[r] + bq) * 0.0625f);
    float fv = accv[r] + bv;
    uv[r] = f2bf(fv);
    vb[(size_t)(r0 + r) * DIMC + tid] = uv[r];
  }
  // transposed store: vtb[b][d=tid][s0..s0+15]  (32B contiguous per thread)
  const int bb = r0 >> 12;
  const int s0 = r0 & (NS - 1);
  uint p[8];
  #pragma unroll
  for (int i = 0; i < 8; ++i)
    p[i] = (uint)uv[2 * i] | ((uint)uv[2 * i + 1] << 16);
  ushort* dst = vtb + ((size_t)(bb * DIMC + tid)) * NS + s0;
  uint4 lo; lo.x = p[0]; lo.y = p[1]; lo.z = p[2]; lo.w = p[3];
  uint4 hi; hi.x = p[4]; hi.y = p[5]; hi.z = p[6]; hi.w = p[7];
  *(uint4*)(dst)     = lo;
  *(uint4*)(dst + 8) = hi;
}

// ---------------- flash attention (q @ v^T softmax @ v) ----------------
// 4 waves/block, each wave owns 16 q rows; 64 q rows per block; KT=64 keys/tile.
__global__ __launch_bounds__(256) void attn_kernel(
    const ushort* __restrict__ qb, const ushort* __restrict__ vb,
    const ushort* __restrict__ vtb, const int* __restrict__ mask,
    float* __restrict__ out)
{
  const int tid  = threadIdx.x;
  const int wave = tid >> 6;
  const int lane = tid & 63;
  const int l15  = lane & 15;
  const int g    = lane >> 4;

  const int qrow0 = blockIdx.x << 6;   // 64 q rows per block (never straddles batch)
  const int bb    = qrow0 >> 12;
  const int moff  = bb << 12;

  // LDS: all tiles stored as swizzled/structured 16B chunks (8 bf16)
  __shared__ ushort qs[64 * 256];                  // chunk(row,c) = row*32 + (c^(row&7))
  __shared__ ushort vs[KT * 256];                  // same swizzle, row = key
  __shared__ ushort vt2[(KT / 8) * 256 * 8];       // [kchunk][dim] -> 8 keys each
  __shared__ __align__(16) ushort ps[4][16][72];   // per-wave P tile [16 q][64 key], stride 72

  // stage q once (64 rows x 32 chunks)
  for (int i = 0; i < 8; ++i) {
    int idx = i * 256 + tid;
    int row = idx >> 5, c = idx & 31;
    *(uint4*)&qs[(row * 32 + (c ^ (row & 7))) * 8] =
        *(const uint4*)&qb[(size_t)(qrow0 + row) * DIMC + c * 8];
  }

  f32x4 acc_o[16];
  #pragma unroll
  for (int nt = 0; nt < 16; ++nt) { acc_o[nt].x = 0.f; acc_o[nt].y = 0.f; acc_o[nt].z = 0.f; acc_o[nt].w = 0.f; }
  float m_r[4] = {-1e30f, -1e30f, -1e30f, -1e30f};
  float l_r[4] = {0.f, 0.f, 0.f, 0.f};

  const int qrow_loc = (wave << 4) + l15;
  const int qswz = qrow_loc & 7;

  for (int kt = 0; kt < NTILES; ++kt) {
    __syncthreads();   // prior tile's reads of vs/vt2 done (also orders qs stage at kt=0)
    // stage v tile: row-major (for QK^T B-frags) and key-chunked transpose (for PV B-frags)
    for (int i = 0; i < 8; ++i) {
      int idx = i * 256 + tid;
      int row = idx >> 5, c = idx & 31;
      *(uint4*)&vs[(row * 32 + (c ^ (row & 7))) * 8] =
          *(const uint4*)&vb[((size_t)(bb * NS + kt * KT + row)) * DIMC + c * 8];
      *(uint4*)&vt2[(i * 256 + tid) * 8] =
          *(const uint4*)&vtb[((size_t)(bb * DIMC + tid)) * NS + kt * KT + i * 8];
    }
    __syncthreads();

    // ---- QK^T: S[16 q][64 key] over 256 dims; A and B frags use identical chunk
    // pattern so the intra-K lane mapping cancels. q was pre-scaled by 1/16.
    f32x4 sacc[4];
    #pragma unroll
    for (int nt = 0; nt < 4; ++nt) { sacc[nt].x=0.f; sacc[nt].y=0.f; sacc[nt].z=0.f; sacc[nt].w=0.f; }
    #pragma unroll
    for (int st = 0; st < 8; ++st) {
      bf16x8 af = *(const bf16x8*)&qs[(qrow_loc * 32 + ((st * 4 + g) ^ qswz)) * 8];
      #pragma unroll
      for (int nt = 0; nt < 4; ++nt) {
        int key = nt * 16 + l15;
        bf16x8 bf = *(const bf16x8*)&vs[(key * 32 + ((st * 4 + g) ^ (key & 7))) * 8];
        sacc[nt] = __builtin_amdgcn_mfma_f32_16x16x32_bf16(af, bf, sacc[nt], 0, 0, 0);
      }
    }

    // ---- mask + online softmax (D-frag: col=key=l15(+16nt), row=4g+r  [verified map])
    int alive[4];
    #pragma unroll
    for (int nt = 0; nt < 4; ++nt)
      alive[nt] = mask[moff + kt * KT + nt * 16 + l15];

    float p[4][4];
    float sc[4];
    #pragma unroll
    for (int r = 0; r < 4; ++r) {
      float v0 = alive[0] ? sacc[0][r] : -1e30f;
      float v1 = alive[1] ? sacc[1][r] : -1e30f;
      float v2 = alive[2] ? sacc[2][r] : -1e30f;
      float v3 = alive[3] ? sacc[3][r] : -1e30f;
      float tm = fmaxf(fmaxf(v0, v1), fmaxf(v2, v3));
      tm = fmaxf(tm, __shfl_xor(tm, 1));
      tm = fmaxf(tm, __shfl_xor(tm, 2));
      tm = fmaxf(tm, __shfl_xor(tm, 4));
      tm = fmaxf(tm, __shfl_xor(tm, 8));
      float mo = m_r[r];
      float mn = fmaxf(mo, tm);
      float scale = __expf(mo - mn);        // mo=mn=-1e30 -> 1, but acc/l are 0: safe
      float p0 = (v0 > -1e29f) ? __expf(v0 - mn) : 0.f;
      float p1 = (v1 > -1e29f) ? __expf(v1 - mn) : 0.f;
      float p2 = (v2 > -1e29f) ? __expf(v2 - mn) : 0.f;
      float p3 = (v3 > -1e29f) ? __expf(v3 - mn) : 0.f;
      float rs = (p0 + p1) + (p2 + p3);
      rs += __shfl_xor(rs, 1);
      rs += __shfl_xor(rs, 2);
      rs += __shfl_xor(rs, 4);
      rs += __shfl_xor(rs, 8);
      m_r[r] = mn;
      l_r[r] = l_r[r] * scale + rs;
      sc[r] = scale;
      p[0][r] = p0; p[1][r] = p1; p[2][r] = p2; p[3][r] = p3;
    }
    f32x4 scv; scv.x = sc[0]; scv.y = sc[1]; scv.z = sc[2]; scv.w = sc[3];
    #pragma unroll
    for (int nt = 0; nt < 16; ++nt) acc_o[nt] *= scv;

    // write P (true row = 4g+r, true col = nt*16+l15); per-wave buffer, wave-internal
    // LDS RAW dependency -> compiler-ordered, no barrier needed
    #pragma unroll
    for (int nt = 0; nt < 4; ++nt) {
      #pragma unroll
      for (int r = 0; r < 4; ++r)
        ps[wave][4 * g + r][nt * 16 + l15] = f2bf(p[nt][r]);
    }

    // ---- PV: out[16 q][256 d] += P[16][64] @ V[64][256]
    #pragma unroll
    for (int ks = 0; ks < 2; ++ks) {
      bf16x8 pa = *(const bf16x8*)&ps[wave][l15][ks * 32 + 8 * g];
      #pragma unroll
      for (int nt = 0; nt < 16; ++nt) {
        bf16x8 vf = *(const bf16x8*)&vt2[(((ks * 4 + g) * 256) + nt * 16 + l15) * 8];
        acc_o[nt] = __builtin_amdgcn_mfma_f32_16x16x32_bf16(pa, vf, acc_o[nt], 0, 0, 0);
      }
    }
  }

  // epilogue: divide by softmax denom, write fp32
  f32x4 linv;
  linv.x = 1.f / l_r[0]; linv.y = 1.f / l_r[1]; linv.z = 1.f / l_r[2]; linv.w = 1.f / l_r[3];
  #pragma unroll
  for (int nt = 0; nt < 16; ++nt) {
    f32x4 o = acc_o[nt] * linv;
    #pragma unroll
    for (int r = 0; r < 4; ++r) {
      int row = qrow0 + (wave << 4) + 4 * g + r;
      out[(size_t)row * DIMC + nt * 16 + l15] = o[r];
    }
  }
}

extern "C" void kernel_launch(void* const* d_in, const int* in_sizes, int n_in,
                              void* d_out, int out_size, void* d_ws, size_t ws_size,
                              hipStream_t stream) {
  const float* x    = (const float*)d_in[0];
  const float* W    = (const float*)d_in[1];
  const float* bias = (const float*)d_in[2];
  const int*   mask = (const int*)d_in[3];
  float* out = (float*)d_out;

  const size_t n = (size_t)NB * NS * DIMC;      // 4.19M elements
  ushort* qb  = (ushort*)d_ws;                  // 8 MB
  ushort* vb  = qb + n;                         // 8 MB
  ushort* vtb = vb + n;                         // 8 MB  (total 24 MB of d_ws)

  qv_proj_kernel<<<(NB * NS) / 16, 256, 0, stream>>>(x, W, bias, qb, vb, vtb);
  attn_kernel<<<(NB * NS) / 64, 256, 0, stream>>>(qb, vb, vtb, mask, out);
}

// Round 2
// 331.874 us; speedup vs baseline: 1.1375x; 1.1375x over previous
//
#include <hip/hip_runtime.h>
#include <hip/hip_bf16.h>

#define DIMC 256
#define NB 4
#define NS 4096
#define KT 64               // keys per tile in attention
#define NTILES (NS / KT)
#define VS_ELEMS (KT * DIMC)   // 16384 ushorts per tile buffer

typedef __attribute__((ext_vector_type(4))) float f32x4;
typedef __attribute__((ext_vector_type(8))) short bf16x8;

__device__ __forceinline__ ushort f2bf(float f) {
  __hip_bfloat16 h = __float2bfloat16(f);
  return *reinterpret_cast<ushort*>(&h);
}

// async global->LDS DMA, 16B per lane; LDS dest is wave-uniform base (+lane*16 in HW)
__device__ __forceinline__ void gload16(const ushort* g, ushort* l) {
  __builtin_amdgcn_global_load_lds(
      (const __attribute__((address_space(1))) unsigned int*)g,
      (__attribute__((address_space(3))) unsigned int*)l,
      16, 0, 0);
}

// ---------------- QV projection ----------------
// qb  = (x @ Wq^T + bq) * (1/16)   row-major [B*S][256] bf16 (pre-scaled)
// vb  =  x @ Wv^T + bv             row-major [B*S][256] bf16
// vtb =  v transposed per batch    [B][256][S] bf16
__global__ __launch_bounds__(256) void qv_proj_kernel(
    const float* __restrict__ x, const float* __restrict__ W,
    const float* __restrict__ bias,
    ushort* __restrict__ qb, ushort* __restrict__ vb, ushort* __restrict__ vtb)
{
  const int tid = threadIdx.x;
  const int r0 = blockIdx.x << 5;     // 32 rows per block
  __shared__ float xs[32][260];
  #pragma unroll
  for (int i = 0; i < 32; ++i)
    xs[i][tid] = x[(size_t)(r0 + i) * DIMC + tid];
  __syncthreads();

  const float4* wq = (const float4*)(W + (size_t)tid * DIMC);          // q row
  const float4* wv = (const float4*)(W + (size_t)(512 + tid) * DIMC);  // v row
  float accq[32], accv[32];
  #pragma unroll
  for (int r = 0; r < 32; ++r) { accq[r] = 0.f; accv[r] = 0.f; }
  for (int j4 = 0; j4 < 64; ++j4) {
    float4 a = wq[j4];
    float4 c = wv[j4];
    #pragma unroll
    for (int r = 0; r < 32; ++r) {
      float4 xv = *(const float4*)&xs[r][j4 * 4];
      accq[r] = fmaf(xv.x, a.x, fmaf(xv.y, a.y, fmaf(xv.z, a.z, fmaf(xv.w, a.w, accq[r]))));
      accv[r] = fmaf(xv.x, c.x, fmaf(xv.y, c.y, fmaf(xv.z, c.z, fmaf(xv.w, c.w, accv[r]))));
    }
  }
  const float bq = bias[tid];
  const float bv = bias[512 + tid];
  ushort uv[32];
  #pragma unroll
  for (int r = 0; r < 32; ++r) {
    qb[(size_t)(r0 + r) * DIMC + tid] = f2bf((accq[r] + bq) * 0.0625f);
    float fv = accv[r] + bv;
    uv[r] = f2bf(fv);
    vb[(size_t)(r0 + r) * DIMC + tid] = uv[r];
  }
  const int bbp = r0 >> 12;
  const int s0 = r0 & (NS - 1);
  uint p[16];
  #pragma unroll
  for (int i = 0; i < 16; ++i)
    p[i] = (uint)uv[2 * i] | ((uint)uv[2 * i + 1] << 16);
  ushort* dst = vtb + ((size_t)(bbp * DIMC + tid)) * NS + s0;
  uint4 q0; q0.x = p[0];  q0.y = p[1];  q0.z = p[2];  q0.w = p[3];
  uint4 q1; q1.x = p[4];  q1.y = p[5];  q1.z = p[6];  q1.w = p[7];
  uint4 q2; q2.x = p[8];  q2.y = p[9];  q2.z = p[10]; q2.w = p[11];
  uint4 q3; q3.x = p[12]; q3.y = p[13]; q3.z = p[14]; q3.w = p[15];
  *(uint4*)(dst)      = q0;
  *(uint4*)(dst + 8)  = q1;
  *(uint4*)(dst + 16) = q2;
  *(uint4*)(dst + 24) = q3;
}

// ---------------- mask -> packed bits ----------------
// packed[b][l15][w]: bit j corresponds to key = 16*(32w+j) + l15
__global__ void mask_pack_kernel(const int* __restrict__ mask, uint* __restrict__ packed) {
  int t = blockIdx.x * 64 + threadIdx.x;   // 512 threads total
  int b = t >> 7;
  int l15 = (t >> 3) & 15;
  int w = t & 7;
  const int* mrow = mask + b * NS;
  uint word = 0;
  for (int j = 0; j < 32; ++j) {
    int key = ((w * 32 + j) << 4) + l15;
    if (mrow[key] != 0) word |= (1u << j);
  }
  packed[t] = word;
}

// ---------------- flash attention (q @ v^T softmax @ v) ----------------
// 4 waves/block, each wave owns 16 q rows; KT=64 keys/tile; async dbuf pipeline.
__global__ __launch_bounds__(256, 1) void attn_kernel(
    const ushort* __restrict__ qb, const ushort* __restrict__ vb,
    const ushort* __restrict__ vtb, const uint* __restrict__ packed,
    float* __restrict__ out)
{
  const int tid  = threadIdx.x;
  const int wave = tid >> 6;
  const int lane = tid & 63;
  const int l15  = lane & 15;
  const int g    = (lane >> 4) & 3;

  const int qrow0 = blockIdx.x << 6;   // 64 q rows per block
  const int bb    = qrow0 >> 12;

  extern __shared__ __align__(16) char smem[];
  uint*   mlds = (uint*)smem;                         // 16*9 uints (padded stride)
  ushort* vs0  = (ushort*)(smem + 1024);              // 2 x 16384 (key-major V, swizzled)
  ushort* vt0  = vs0 + 2 * VS_ELEMS;                  // 2 x 16384 (V^T 8-key chunks, swizzled)
  ushort* psb  = vt0 + 2 * VS_ELEMS;                  // 4 waves x 16 x 72

  ushort* vs1 = vs0 + VS_ELEMS;
  ushort* vt1 = vt0 + VS_ELEMS;

  // ---- Q into registers: qreg[st] = logical chunk (st*4+g) of this lane's q-row
  const int qrow = qrow0 + (wave << 4) + l15;
  bf16x8 qreg[8];
  #pragma unroll
  for (int st = 0; st < 8; ++st)
    qreg[st] = *(const bf16x8*)&qb[(size_t)qrow * DIMC + ((st * 4 + g) << 3)];

  // ---- mask bits into padded LDS
  if (tid < 128) mlds[(tid >> 3) * 9 + (tid & 7)] = packed[(bb << 7) + tid];

  // ---- prologue: stage tile 0 into buf 0
  {
    const ushort* vbase = vb + ((size_t)(bb * NS)) * DIMC;
    #pragma unroll
    for (int i = 0; i < 8; ++i) {
      int rr0 = (wave << 4) + i * 2;
      int row = rr0 + (lane >> 5);
      int cs  = lane & 31;
      gload16(vbase + row * DIMC + ((cs ^ (row & 7)) << 3), vs0 + (rr0 << 8));
    }
    #pragma unroll
    for (int i = 0; i < 8; ++i) {
      int kc = (wave << 1) + (i >> 2);
      int d0 = (i & 3) << 6;
      int dim = (d0 + lane) ^ ((kc & 3) << 1);
      gload16(vtb + ((size_t)(bb * DIMC + dim)) * NS + (kc << 3),
              vt0 + ((kc << 8) + d0) * 8);
    }
  }
  asm volatile("s_waitcnt vmcnt(0)" ::: "memory");
  __syncthreads();

  f32x4 acc_o[16];
  #pragma unroll
  for (int nt = 0; nt < 16; ++nt) { acc_o[nt].x = 0.f; acc_o[nt].y = 0.f; acc_o[nt].z = 0.f; acc_o[nt].w = 0.f; }
  float m_r[4] = {-1e30f, -1e30f, -1e30f, -1e30f};
  float l_r[4] = {0.f, 0.f, 0.f, 0.f};

  ushort* psw = psb + wave * (16 * 72);

  auto tile_body = [&](int kt, const ushort* vs_, const ushort* vt_,
                       ushort* vsN, ushort* vtN) {
    // ---- stage next tile (async; completes by the barrier at the end)
    if (kt + 1 < NTILES) {
      const int kt1 = kt + 1;
      const ushort* vbase = vb + ((size_t)(bb * NS + kt1 * KT)) * DIMC;
      #pragma unroll
      for (int i = 0; i < 8; ++i) {
        int rr0 = (wave << 4) + i * 2;
        int row = rr0 + (lane >> 5);
        int cs  = lane & 31;
        gload16(vbase + row * DIMC + ((cs ^ (row & 7)) << 3), vsN + (rr0 << 8));
      }
      #pragma unroll
      for (int i = 0; i < 8; ++i) {
        int kc = (wave << 1) + (i >> 2);
        int d0 = (i & 3) << 6;
        int dim = (d0 + lane) ^ ((kc & 3) << 1);
        gload16(vtb + ((size_t)(bb * DIMC + dim)) * NS + kt1 * KT + (kc << 3),
                vtN + ((kc << 8) + d0) * 8);
      }
    }

    // ---- QK^T: S[16 q][64 key]; A and B use identical logical-chunk pattern
    f32x4 sacc[4];
    #pragma unroll
    for (int nt = 0; nt < 4; ++nt) { sacc[nt].x=0.f; sacc[nt].y=0.f; sacc[nt].z=0.f; sacc[nt].w=0.f; }
    #pragma unroll
    for (int st = 0; st < 8; ++st) {
      #pragma unroll
      for (int nt = 0; nt < 4; ++nt) {
        int key = nt * 16 + l15;
        bf16x8 bf = *(const bf16x8*)&vs_[(key * 32 + ((st * 4 + g) ^ (key & 7))) * 8];
        sacc[nt] = __builtin_amdgcn_mfma_f32_16x16x32_bf16(qreg[st], bf, sacc[nt], 0, 0, 0);
      }
    }

    // ---- mask bits for this tile (bits 0..3 = alive for nt 0..3 at this l15)
    uint mw = mlds[(l15 << 3) + l15 + (kt >> 3)] >> ((kt & 7) << 2);  // l15*9 + kt/8

    // ---- online softmax with defer-rescale
    float pr[4][4], rsv[4], mnv[4];
    bool grow = false;
    #pragma unroll
    for (int r = 0; r < 4; ++r) {
      float v0 = (mw & 1u) ? sacc[0][r] : -1e30f;
      float v1 = (mw & 2u) ? sacc[1][r] : -1e30f;
      float v2 = (mw & 4u) ? sacc[2][r] : -1e30f;
      float v3 = (mw & 8u) ? sacc[3][r] : -1e30f;
      float tm = fmaxf(fmaxf(v0, v1), fmaxf(v2, v3));
      tm = fmaxf(tm, __shfl_xor(tm, 1));
      tm = fmaxf(tm, __shfl_xor(tm, 2));
      tm = fmaxf(tm, __shfl_xor(tm, 4));
      tm = fmaxf(tm, __shfl_xor(tm, 8));
      float mo = m_r[r];
      float mn = fmaxf(mo, tm);
      grow = grow || (mn > mo);
      float p0 = (v0 > -1e29f) ? __expf(v0 - mn) : 0.f;
      float p1 = (v1 > -1e29f) ? __expf(v1 - mn) : 0.f;
      float p2 = (v2 > -1e29f) ? __expf(v2 - mn) : 0.f;
      float p3 = (v3 > -1e29f) ? __expf(v3 - mn) : 0.f;
      float rs = (p0 + p1) + (p2 + p3);
      rs += __shfl_xor(rs, 1);
      rs += __shfl_xor(rs, 2);
      rs += __shfl_xor(rs, 4);
      rs += __shfl_xor(rs, 8);
      mnv[r] = mn; rsv[r] = rs;
      pr[0][r] = p0; pr[1][r] = p1; pr[2][r] = p2; pr[3][r] = p3;
    }
    if (__any((int)grow)) {
      f32x4 scv;
      #pragma unroll
      for (int r = 0; r < 4; ++r) {
        float sc = __expf(m_r[r] - mnv[r]);
        m_r[r] = mnv[r];
        l_r[r] = l_r[r] * sc + rsv[r];
        scv[r] = sc;
      }
      #pragma unroll
      for (int nt = 0; nt < 16; ++nt) acc_o[nt] *= scv;
    } else {
      #pragma unroll
      for (int r = 0; r < 4; ++r) l_r[r] += rsv[r];
    }

    // ---- P to LDS (verified C-map: row=4g+r, col=nt*16+l15); wave-local
    #pragma unroll
    for (int nt = 0; nt < 4; ++nt) {
      #pragma unroll
      for (int r = 0; r < 4; ++r)
        psw[(4 * g + r) * 72 + nt * 16 + l15] = f2bf(pr[nt][r]);
    }

    // ---- PV: out[16 q][256 d] += P[16][64] @ V[64][256]
    #pragma unroll
    for (int ks = 0; ks < 2; ++ks) {
      bf16x8 pa = *(const bf16x8*)&psw[l15 * 72 + ks * 32 + 8 * g];
      #pragma unroll
      for (int nt = 0; nt < 16; ++nt) {
        bf16x8 vf = *(const bf16x8*)&vt_[(((ks * 4 + g) << 8) + ((nt * 16 + l15) ^ (g << 1))) * 8];
        acc_o[nt] = __builtin_amdgcn_mfma_f32_16x16x32_bf16(pa, vf, acc_o[nt], 0, 0, 0);
      }
    }

    asm volatile("s_waitcnt vmcnt(0)" ::: "memory");
    __syncthreads();
  };

  for (int kt2 = 0; kt2 < NTILES; kt2 += 2) {
    tile_body(kt2,     vs0, vt0, vs1, vt1);
    tile_body(kt2 + 1, vs1, vt1, vs0, vt0);
  }

  // ---- epilogue
  f32x4 linv;
  linv.x = 1.f / l_r[0]; linv.y = 1.f / l_r[1]; linv.z = 1.f / l_r[2]; linv.w = 1.f / l_r[3];
  #pragma unroll
  for (int nt = 0; nt < 16; ++nt) {
    f32x4 o = acc_o[nt] * linv;
    #pragma unroll
    for (int r = 0; r < 4; ++r) {
      int row = qrow0 + (wave << 4) + 4 * g + r;
      out[(size_t)row * DIMC + nt * 16 + l15] = o[r];
    }
  }
}

extern "C" void kernel_launch(void* const* d_in, const int* in_sizes, int n_in,
                              void* d_out, int out_size, void* d_ws, size_t ws_size,
                              hipStream_t stream) {
  const float* x    = (const float*)d_in[0];
  const float* W    = (const float*)d_in[1];
  const float* bias = (const float*)d_in[2];
  const int*   mask = (const int*)d_in[3];
  float* out = (float*)d_out;

  const size_t n = (size_t)NB * NS * DIMC;      // 4.19M elements
  ushort* qb  = (ushort*)d_ws;                  // 8 MB
  ushort* vb  = qb + n;                         // 8 MB
  ushort* vtb = vb + n;                         // 8 MB
  uint* packed = (uint*)(vtb + n);              // 2 KB

  qv_proj_kernel<<<(NB * NS) / 32, 256, 0, stream>>>(x, W, bias, qb, vb, vtb);
  mask_pack_kernel<<<8, 64, 0, stream>>>(mask, packed);

  const int smem_bytes = 1024 + 4 * VS_ELEMS * 2 + 4 * 16 * 72 * 2;  // 141 KB
  attn_kernel<<<(NB * NS) / 64, 256, smem_bytes, stream>>>(qb, vb, vtb, packed, out);
}

// Round 3
// 251.631 us; speedup vs baseline: 1.5002x; 1.3189x over previous
//
#include <hip/hip_runtime.h>
#include <hip/hip_bf16.h>

#define DIMC 256
#define NB 4
#define NS 4096
#define KT 64               // keys per tile in attention
#define NTILES (NS / KT)
#define VS_ELEMS (KT * DIMC)   // 16384 ushorts per 32KB tile buffer

typedef __attribute__((ext_vector_type(4))) float f32x4;
typedef __attribute__((ext_vector_type(8))) short bf16x8;

__device__ __forceinline__ ushort f2bf(float f) {
  __hip_bfloat16 h = __float2bfloat16(f);
  return *reinterpret_cast<ushort*>(&h);
}

// async global->LDS DMA, 16B per lane; LDS dest = wave-uniform base + lane*16
__device__ __forceinline__ void gload16(const ushort* g, ushort* l) {
  __builtin_amdgcn_global_load_lds(
      (const __attribute__((address_space(1))) unsigned int*)g,
      (__attribute__((address_space(3))) unsigned int*)l,
      16, 0, 0);
}

// ---------------- W transpose (once): Wt[k][c] ----------------
// c in [0,256): q output col (W row c);  c in [256,512): v output col (W row 512+c-256)
__global__ void wtrans_kernel(const float* __restrict__ W, float* __restrict__ Wt) {
  const int c = blockIdx.x;            // 0..511
  const int k = threadIdx.x;           // 0..255
  const int srcrow = (c < 256) ? c : (c + 256);
  Wt[(size_t)k * 512 + c] = W[(size_t)srcrow * 256 + k];
}

// ---------------- QV projection ----------------
// qb = (x @ Wq^T + bq)/16 bf16 [B*S][256];  vb = x @ Wv^T + bv bf16 [B*S][256]
// vtb = v transposed per batch [B][256][S] bf16
__global__ __launch_bounds__(256) void qv_proj_kernel(
    const float* __restrict__ x, const float* __restrict__ Wt,
    const float* __restrict__ bias,
    ushort* __restrict__ qb, ushort* __restrict__ vb, ushort* __restrict__ vtb)
{
  const int tid = threadIdx.x;
  const int r0 = blockIdx.x << 4;     // 16 rows per block
  __shared__ float xsT[256][20];      // xsT[k][r]; stride 20 -> aligned float4 rows
  #pragma unroll
  for (int i = 0; i < 16; ++i)
    xsT[tid][i] = x[(size_t)(r0 + i) * DIMC + tid];
  __syncthreads();

  float accq[16], accv[16];
  #pragma unroll
  for (int r = 0; r < 16; ++r) { accq[r] = 0.f; accv[r] = 0.f; }

  #pragma unroll 2
  for (int k = 0; k < 256; ++k) {
    const float wq = Wt[(size_t)k * 512 + tid];        // coalesced
    const float wv = Wt[(size_t)k * 512 + 256 + tid];  // coalesced
    #pragma unroll
    for (int r4 = 0; r4 < 4; ++r4) {
      float4 xv = *(const float4*)&xsT[k][r4 * 4];     // broadcast
      accq[r4*4+0] = fmaf(xv.x, wq, accq[r4*4+0]);
      accq[r4*4+1] = fmaf(xv.y, wq, accq[r4*4+1]);
      accq[r4*4+2] = fmaf(xv.z, wq, accq[r4*4+2]);
      accq[r4*4+3] = fmaf(xv.w, wq, accq[r4*4+3]);
      accv[r4*4+0] = fmaf(xv.x, wv, accv[r4*4+0]);
      accv[r4*4+1] = fmaf(xv.y, wv, accv[r4*4+1]);
      accv[r4*4+2] = fmaf(xv.z, wv, accv[r4*4+2]);
      accv[r4*4+3] = fmaf(xv.w, wv, accv[r4*4+3]);
    }
  }
  const float bq = bias[tid];
  const float bv = bias[512 + tid];
  ushort uv[16];
  #pragma unroll
  for (int r = 0; r < 16; ++r) {
    qb[(size_t)(r0 + r) * DIMC + tid] = f2bf((accq[r] + bq) * 0.0625f);
    float fv = accv[r] + bv;
    uv[r] = f2bf(fv);
    vb[(size_t)(r0 + r) * DIMC + tid] = uv[r];
  }
  const int bbp = r0 >> 12;
  const int s0 = r0 & (NS - 1);
  uint p[8];
  #pragma unroll
  for (int i = 0; i < 8; ++i)
    p[i] = (uint)uv[2 * i] | ((uint)uv[2 * i + 1] << 16);
  ushort* dst = vtb + ((size_t)(bbp * DIMC + tid)) * NS + s0;
  uint4 lo; lo.x = p[0]; lo.y = p[1]; lo.z = p[2]; lo.w = p[3];
  uint4 hi; hi.x = p[4]; hi.y = p[5]; hi.z = p[6]; hi.w = p[7];
  *(uint4*)(dst)     = lo;
  *(uint4*)(dst + 8) = hi;
}

// ---------------- mask -> packed bits ----------------
// packed[b][l15][w]: bit j corresponds to key = 16*(32w+j) + l15
__global__ void mask_pack_kernel(const int* __restrict__ mask, uint* __restrict__ packed) {
  int t = blockIdx.x * 64 + threadIdx.x;   // 512 threads total
  int b = t >> 7;
  int l15 = (t >> 3) & 15;
  int w = t & 7;
  const int* mrow = mask + b * NS;
  uint word = 0;
  for (int j = 0; j < 32; ++j) {
    int key = ((w * 32 + j) << 4) + l15;
    if (mrow[key] != 0) word |= (1u << j);
  }
  packed[t] = word;
}

// ---------------- flash attention (q @ v^T softmax @ v) ----------------
// 8 waves/block: wave w = (pair pq = w>>1, key-half kh = w&1).
// Each wave: 16 q rows x its 32-key half of every 64-key tile, with its OWN
// online-softmax state; flash-merge across the pair at the epilogue.
__global__ __launch_bounds__(512, 2) void attn_kernel(
    const ushort* __restrict__ qb, const ushort* __restrict__ vb,
    const ushort* __restrict__ vtb, const uint* __restrict__ packed,
    float* __restrict__ out)
{
  const int tid  = threadIdx.x;
  const int w    = tid >> 6;
  const int lane = tid & 63;
  const int l15  = lane & 15;
  const int g    = (lane >> 4) & 3;
  const int kh   = w & 1;        // key half
  const int pq   = w >> 1;       // q-tile pair index

  const int qrow0 = blockIdx.x << 6;   // 64 q rows per block
  const int bb    = qrow0 >> 12;

  extern __shared__ __align__(16) char smem[];
  uint*   mlds = (uint*)smem;                         // 1KB (16*9 uints padded)
  ushort* vs0  = (ushort*)(smem + 1024);              // 32KB key-major V (swizzled)
  ushort* vs1  = vs0 + VS_ELEMS;                      // 32KB
  ushort* vt0  = vs1 + VS_ELEMS;                      // 32KB V^T 8-key chunks (swizzled)
  ushort* vt1  = vt0 + VS_ELEMS;                      // 32KB
  ushort* psb  = vt1 + VS_ELEMS;                      // 8 waves x 16 x 40 = 10KB

  // ---- Q into registers
  const int qrow = qrow0 + (pq << 4) + l15;
  bf16x8 qreg[8];
  #pragma unroll
  for (int st = 0; st < 8; ++st)
    qreg[st] = *(const bf16x8*)&qb[(size_t)qrow * DIMC + ((st * 4 + g) << 3)];

  if (tid < 128) mlds[(tid >> 3) * 9 + (tid & 7)] = packed[(bb << 7) + tid];

  // ---- staging helper (8 waves cooperate; 8 gloads per lane per tile)
  auto stage = [&](int kt, ushort* vsN, ushort* vtN) {
    const ushort* vbase = vb + ((size_t)(bb * NS + kt * KT)) * DIMC;
    #pragma unroll
    for (int i = 0; i < 4; ++i) {
      int rr0 = (w << 3) + (i << 1);
      int row = rr0 + (lane >> 5);
      int cs  = lane & 31;
      gload16(vbase + row * DIMC + ((cs ^ (row & 7)) << 3), vsN + (rr0 << 8));
    }
    #pragma unroll
    for (int i = 0; i < 4; ++i) {
      int d0 = i << 6;
      int dim = (d0 + lane) ^ ((w & 3) << 1);
      gload16(vtb + ((size_t)(bb * DIMC + dim)) * NS + kt * KT + (w << 3),
              vtN + ((w << 8) + d0) * 8);
    }
  };

  stage(0, vs0, vt0);
  asm volatile("s_waitcnt vmcnt(0)" ::: "memory");
  __syncthreads();

  f32x4 acc_o[16];
  #pragma unroll
  for (int nt = 0; nt < 16; ++nt) { acc_o[nt].x=0.f; acc_o[nt].y=0.f; acc_o[nt].z=0.f; acc_o[nt].w=0.f; }
  float m_r[4] = {-1e30f, -1e30f, -1e30f, -1e30f};
  float l_r[4] = {0.f, 0.f, 0.f, 0.f};

  ushort* psw = psb + w * (16 * 40);

  auto tile_body = [&](int kt, const ushort* vs_, const ushort* vt_,
                       ushort* vsN, ushort* vtN) {
    if (kt + 1 < NTILES) stage(kt + 1, vsN, vtN);

    // ---- QK^T: S[16 q][32 key (this wave's half)]
    f32x4 sacc[2];
    sacc[0].x=0.f; sacc[0].y=0.f; sacc[0].z=0.f; sacc[0].w=0.f;
    sacc[1] = sacc[0];
    __builtin_amdgcn_s_setprio(1);
    #pragma unroll
    for (int st = 0; st < 8; ++st) {
      #pragma unroll
      for (int ntl = 0; ntl < 2; ++ntl) {
        int key = ((kh << 1) + ntl) * 16 + l15;
        bf16x8 bf = *(const bf16x8*)&vs_[(key * 32 + ((st * 4 + g) ^ (key & 7))) * 8];
        sacc[ntl] = __builtin_amdgcn_mfma_f32_16x16x32_bf16(qreg[st], bf, sacc[ntl], 0, 0, 0);
      }
    }
    __builtin_amdgcn_s_setprio(0);

    // ---- mask bits (bit0/bit1 = alive for our two 16-key groups at this l15)
    uint mw = (mlds[l15 * 9 + (kt >> 3)] >> ((kt & 7) << 2)) >> (kh << 1);

    // ---- online softmax (this wave's 32 keys) with defer-rescale
    float pr[2][4], rsv[4], mnv[4];
    bool grow = false;
    #pragma unroll
    for (int r = 0; r < 4; ++r) {
      float v0 = (mw & 1u) ? sacc[0][r] : -1e30f;
      float v1 = (mw & 2u) ? sacc[1][r] : -1e30f;
      float tm = fmaxf(v0, v1);
      tm = fmaxf(tm, __shfl_xor(tm, 1));
      tm = fmaxf(tm, __shfl_xor(tm, 2));
      tm = fmaxf(tm, __shfl_xor(tm, 4));
      tm = fmaxf(tm, __shfl_xor(tm, 8));
      float mo = m_r[r];
      float mn = fmaxf(mo, tm);
      grow = grow || (mn > mo);
      float p0 = (v0 > -1e29f) ? __expf(v0 - mn) : 0.f;
      float p1 = (v1 > -1e29f) ? __expf(v1 - mn) : 0.f;
      float rs = p0 + p1;
      rs += __shfl_xor(rs, 1);
      rs += __shfl_xor(rs, 2);
      rs += __shfl_xor(rs, 4);
      rs += __shfl_xor(rs, 8);
      mnv[r] = mn; rsv[r] = rs;
      pr[0][r] = p0; pr[1][r] = p1;
    }
    if (__any((int)grow)) {
      f32x4 scv;
      #pragma unroll
      for (int r = 0; r < 4; ++r) {
        float sc = __expf(m_r[r] - mnv[r]);
        m_r[r] = mnv[r];
        l_r[r] = l_r[r] * sc + rsv[r];
        scv[r] = sc;
      }
      #pragma unroll
      for (int nt = 0; nt < 16; ++nt) acc_o[nt] *= scv;
    } else {
      #pragma unroll
      for (int r = 0; r < 4; ++r) l_r[r] += rsv[r];
    }

    // ---- P to per-wave LDS tile [16 q][32 key], stride 40
    #pragma unroll
    for (int ntl = 0; ntl < 2; ++ntl) {
      #pragma unroll
      for (int r = 0; r < 4; ++r)
        psw[(4 * g + r) * 40 + (ntl << 4) + l15] = f2bf(pr[ntl][r]);
    }

    // ---- PV: acc_o[16 q][256 d] += P[16][32] @ V[32 keys of our half][256]
    bf16x8 pa = *(const bf16x8*)&psw[l15 * 40 + (g << 3)];
    const int kc = (kh << 2) + g;   // 8-key chunk within the 64-key tile
    __builtin_amdgcn_s_setprio(1);
    #pragma unroll
    for (int nt = 0; nt < 16; ++nt) {
      bf16x8 vf = *(const bf16x8*)&vt_[((kc << 8) + ((nt * 16 + l15) ^ ((kc & 3) << 1))) * 8];
      acc_o[nt] = __builtin_amdgcn_mfma_f32_16x16x32_bf16(pa, vf, acc_o[nt], 0, 0, 0);
    }
    __builtin_amdgcn_s_setprio(0);

    asm volatile("s_waitcnt vmcnt(0)" ::: "memory");
    __syncthreads();
  };

  for (int kt2 = 0; kt2 < NTILES; kt2 += 2) {
    tile_body(kt2,     vs0, vt0, vs1, vt1);
    tile_body(kt2 + 1, vs1, vt1, vs0, vt0);
  }

  // ---- flash-merge across the wave pair (reuses vs/vt LDS space)
  f32x4* accS = (f32x4*)(smem + 1024);              // 4 pairs x 16 x 64 lanes = 64KB
  float* mlS  = (float*)(smem + 1024 + 65536);      // 4 x 64 x 8 = 8KB
  if (kh) {
    #pragma unroll
    for (int nt = 0; nt < 16; ++nt)
      accS[((pq << 4) + nt) * 64 + lane] = acc_o[nt];
    #pragma unroll
    for (int r = 0; r < 4; ++r) {
      mlS[((pq << 6) + lane) * 8 + r]     = m_r[r];
      mlS[((pq << 6) + lane) * 8 + 4 + r] = l_r[r];
    }
  }
  __syncthreads();
  if (!kh) {
    f32x4 fA, fB;
    #pragma unroll
    for (int r = 0; r < 4; ++r) {
      float mB = mlS[((pq << 6) + lane) * 8 + r];
      float lB = mlS[((pq << 6) + lane) * 8 + 4 + r];
      float m  = fmaxf(m_r[r], mB);
      float eA = __expf(m_r[r] - m);
      float eB = __expf(mB - m);
      float inv = 1.f / (l_r[r] * eA + lB * eB);
      fA[r] = eA * inv;
      fB[r] = eB * inv;
    }
    #pragma unroll
    for (int nt = 0; nt < 16; ++nt) {
      f32x4 oB = accS[((pq << 4) + nt) * 64 + lane];
      f32x4 o = acc_o[nt] * fA + oB * fB;
      #pragma unroll
      for (int r = 0; r < 4; ++r) {
        int row = qrow0 + (pq << 4) + 4 * g + r;
        out[(size_t)row * DIMC + nt * 16 + l15] = o[r];
      }
    }
  }
}

extern "C" void kernel_launch(void* const* d_in, const int* in_sizes, int n_in,
                              void* d_out, int out_size, void* d_ws, size_t ws_size,
                              hipStream_t stream) {
  const float* x    = (const float*)d_in[0];
  const float* W    = (const float*)d_in[1];
  const float* bias = (const float*)d_in[2];
  const int*   mask = (const int*)d_in[3];
  float* out = (float*)d_out;

  const size_t n = (size_t)NB * NS * DIMC;      // 4.19M elements
  ushort* qb  = (ushort*)d_ws;                  // 8.4 MB
  ushort* vb  = qb + n;                         // 8.4 MB
  ushort* vtb = vb + n;                         // 8.4 MB
  uint* packed = (uint*)(vtb + n);              // 2 KB
  float* Wt = (float*)(packed + 512);           // 512 KB

  wtrans_kernel<<<512, 256, 0, stream>>>(W, Wt);
  mask_pack_kernel<<<8, 64, 0, stream>>>(mask, packed);
  qv_proj_kernel<<<(NB * NS) / 16, 256, 0, stream>>>(x, Wt, bias, qb, vb, vtb);

  const int smem_bytes = 1024 + 4 * VS_ELEMS * 2 + 8 * 16 * 40 * 2;  // 139 KB
  attn_kernel<<<(NB * NS) / 64, 512, smem_bytes, stream>>>(qb, vb, vtb, packed, out);
}

// Round 4
// 206.738 us; speedup vs baseline: 1.8260x; 1.2171x over previous
//
#include <hip/hip_runtime.h>
#include <hip/hip_bf16.h>

#define DIMC 256
#define NB 4
#define NS 4096
#define KT 64               // keys per tile in attention
#define NTILES (NS / KT)
#define VS_ELEMS (KT * DIMC)   // 16384 ushorts per 32KB tile buffer

typedef __attribute__((ext_vector_type(4))) float f32x4;
typedef __attribute__((ext_vector_type(8))) short bf16x8;

__device__ __forceinline__ ushort f2bf(float f) {
  __hip_bfloat16 h = __float2bfloat16(f);
  return *reinterpret_cast<ushort*>(&h);
}

// async global->LDS DMA, 16B per lane; LDS dest = wave-uniform base + lane*16
__device__ __forceinline__ void gload16(const ushort* g, ushort* l) {
  __builtin_amdgcn_global_load_lds(
      (const __attribute__((address_space(1))) unsigned int*)g,
      (__attribute__((address_space(3))) unsigned int*)l,
      16, 0, 0);
}

// ---------------- W transpose (once): float4-chunked ----------------
// Wt4 element layout: Wt[((k>>2)*512 + c)*4 + (k&3)] = W[srcrow(c)][k]
// so float4 load Wt4[k4*512 + c] = W[srcrow(c)][4k4..4k4+3]
__global__ void wtrans_kernel(const float* __restrict__ W, float* __restrict__ Wt) {
  const int c = blockIdx.x;            // 0..511
  const int k = threadIdx.x;           // 0..255
  const int srcrow = (c < 256) ? c : (c + 256);
  Wt[((size_t)(k >> 2) * 512 + c) * 4 + (k & 3)] = W[(size_t)srcrow * 256 + k];
}

// ---------------- QV projection ----------------
__global__ __launch_bounds__(256) void qv_proj_kernel(
    const float* __restrict__ x, const float* __restrict__ Wt,
    const float* __restrict__ bias,
    ushort* __restrict__ qb, ushort* __restrict__ vb, ushort* __restrict__ vtb)
{
  const int tid = threadIdx.x;
  const int r0 = blockIdx.x << 4;     // 16 rows per block
  __shared__ float xsT[256][20];      // xsT[k][r]
  #pragma unroll
  for (int i = 0; i < 16; ++i)
    xsT[tid][i] = x[(size_t)(r0 + i) * DIMC + tid];
  __syncthreads();

  const float4* Wt4 = (const float4*)Wt;
  float accq[16], accv[16];
  #pragma unroll
  for (int r = 0; r < 16; ++r) { accq[r] = 0.f; accv[r] = 0.f; }

  #pragma unroll 2
  for (int k4 = 0; k4 < 64; ++k4) {
    float4 wqv = Wt4[k4 * 512 + tid];
    float4 wvv = Wt4[k4 * 512 + 256 + tid];
    #pragma unroll
    for (int e = 0; e < 4; ++e) {
      float wq = ((const float*)&wqv)[e];
      float wv = ((const float*)&wvv)[e];
      const int k = k4 * 4 + e;
      #pragma unroll
      for (int r4 = 0; r4 < 4; ++r4) {
        float4 xv = *(const float4*)&xsT[k][r4 * 4];
        accq[r4*4+0] = fmaf(xv.x, wq, accq[r4*4+0]);
        accq[r4*4+1] = fmaf(xv.y, wq, accq[r4*4+1]);
        accq[r4*4+2] = fmaf(xv.z, wq, accq[r4*4+2]);
        accq[r4*4+3] = fmaf(xv.w, wq, accq[r4*4+3]);
        accv[r4*4+0] = fmaf(xv.x, wv, accv[r4*4+0]);
        accv[r4*4+1] = fmaf(xv.y, wv, accv[r4*4+1]);
        accv[r4*4+2] = fmaf(xv.z, wv, accv[r4*4+2]);
        accv[r4*4+3] = fmaf(xv.w, wv, accv[r4*4+3]);
      }
    }
  }
  const float bq = bias[tid];
  const float bv = bias[512 + tid];
  ushort uv[16];
  #pragma unroll
  for (int r = 0; r < 16; ++r) {
    qb[(size_t)(r0 + r) * DIMC + tid] = f2bf((accq[r] + bq) * 0.0625f);
    float fv = accv[r] + bv;
    uv[r] = f2bf(fv);
    vb[(size_t)(r0 + r) * DIMC + tid] = uv[r];
  }
  const int bbp = r0 >> 12;
  const int s0 = r0 & (NS - 1);
  uint p[8];
  #pragma unroll
  for (int i = 0; i < 8; ++i)
    p[i] = (uint)uv[2 * i] | ((uint)uv[2 * i + 1] << 16);
  ushort* dst = vtb + ((size_t)(bbp * DIMC + tid)) * NS + s0;
  uint4 lo; lo.x = p[0]; lo.y = p[1]; lo.z = p[2]; lo.w = p[3];
  uint4 hi; hi.x = p[4]; hi.y = p[5]; hi.z = p[6]; hi.w = p[7];
  *(uint4*)(dst)     = lo;
  *(uint4*)(dst + 8) = hi;
}

// ---------------- mask -> packed words ----------------
// pm32[b][kt][kh]: bit (8g + ntl*4 + r) = mask[b][kt*64 + kh*32 + ntl*16 + 4g + r]
__global__ void mask_pack_kernel(const int* __restrict__ mask, uint* __restrict__ pm32) {
  int t = blockIdx.x * 64 + threadIdx.x;   // 512 threads total
  int b = t >> 7;
  int kt = (t >> 1) & 63;
  int kh = t & 1;
  const int* mrow = mask + b * NS + kt * 64 + kh * 32;
  uint wd = 0;
  for (int g = 0; g < 4; ++g)
    for (int ntl = 0; ntl < 2; ++ntl)
      for (int r = 0; r < 4; ++r)
        if (mrow[ntl * 16 + 4 * g + r] != 0) wd |= 1u << (8 * g + ntl * 4 + r);
  pm32[t] = wd;
}

// ---------------- flash attention (q @ v^T softmax @ v) ----------------
// 8 waves/block: wave = (pq = w>>1 q-tile, kh = w&1 key-half).
// Swapped MFMAs: QK^T computes S^T (lane owns one q-row -> in-lane softmax),
// PV computes O^T = V^T @ P^T. Per-wave online-softmax state is scalar.
__global__ __launch_bounds__(512, 2) void attn_kernel(
    const ushort* __restrict__ qb, const ushort* __restrict__ vb,
    const ushort* __restrict__ vtb, const uint* __restrict__ pm32,
    float* __restrict__ out)
{
  const int tid  = threadIdx.x;
  const int w    = tid >> 6;
  const int lane = tid & 63;
  const int l15  = lane & 15;
  const int g    = (lane >> 4) & 3;
  const int kh   = w & 1;        // key half
  const int pq   = w >> 1;       // q-tile index

  const int qrow0 = blockIdx.x << 6;   // 64 q rows per block
  const int bb    = qrow0 >> 12;

  extern __shared__ __align__(16) char smem[];
  uint*   pmlds = (uint*)smem;                        // 512 B
  ushort* vs0  = (ushort*)(smem + 1024);              // 32KB key-major V (swizzled)
  ushort* vs1  = vs0 + VS_ELEMS;                      // 32KB
  ushort* vt0  = vs1 + VS_ELEMS;                      // 32KB V^T 8-key chunks (swizzled)
  ushort* vt1  = vt0 + VS_ELEMS;                      // 32KB
  ushort* psb  = vt1 + VS_ELEMS;                      // 8 waves x 16 x 40 = 10KB

  // ---- Q into registers (B-frag role: lane l15 = q-col, chunk (st*4+g))
  const int qrow = qrow0 + (pq << 4) + l15;
  bf16x8 qreg[8];
  #pragma unroll
  for (int st = 0; st < 8; ++st)
    qreg[st] = *(const bf16x8*)&qb[(size_t)qrow * DIMC + ((st * 4 + g) << 3)];

  if (tid < 128) pmlds[tid] = pm32[(bb << 7) + tid];

  // ---- staging helper (8 waves cooperate)
  auto stage = [&](int kt, ushort* vsN, ushort* vtN) {
    const ushort* vbase = vb + ((size_t)(bb * NS + kt * KT)) * DIMC;
    #pragma unroll
    for (int i = 0; i < 4; ++i) {
      int rr0 = (w << 3) + (i << 1);
      int row = rr0 + (lane >> 5);
      int cs  = lane & 31;
      gload16(vbase + row * DIMC + ((cs ^ (row & 7)) << 3), vsN + (rr0 << 8));
    }
    #pragma unroll
    for (int i = 0; i < 4; ++i) {
      int d0 = i << 6;
      int dim = (d0 + lane) ^ ((w & 3) << 1);
      gload16(vtb + ((size_t)(bb * DIMC + dim)) * NS + kt * KT + (w << 3),
              vtN + ((w << 8) + d0) * 8);
    }
  };

  stage(0, vs0, vt0);
  asm volatile("s_waitcnt vmcnt(0)" ::: "memory");
  __syncthreads();

  f32x4 acc_o[16];
  #pragma unroll
  for (int nt = 0; nt < 16; ++nt) { acc_o[nt].x=0.f; acc_o[nt].y=0.f; acc_o[nt].z=0.f; acc_o[nt].w=0.f; }
  float m_s = -30.f;   // scores are O(10) max; -30 floor makes exp(masked-m)==0 exact
  float l_s = 0.f;

  ushort* psw = psb + w * (16 * 40);

  auto tile_body = [&](int kt, const ushort* vs_, const ushort* vt_,
                       ushort* vsN, ushort* vtN) {
    if (kt + 1 < NTILES) stage(kt + 1, vsN, vtN);

    // ---- QK^T (swapped): S^T[key 4g+r + 16ntl][q l15] for our kh half
    f32x4 sacc[2];
    sacc[0].x=0.f; sacc[0].y=0.f; sacc[0].z=0.f; sacc[0].w=0.f;
    sacc[1] = sacc[0];
    __builtin_amdgcn_s_setprio(1);
    #pragma unroll
    for (int st = 0; st < 8; ++st) {
      #pragma unroll
      for (int ntl = 0; ntl < 2; ++ntl) {
        int key = ((kh << 1) + ntl) * 16 + l15;   // A-frag row = key
        bf16x8 af = *(const bf16x8*)&vs_[(key * 32 + ((st * 4 + g) ^ (key & 7))) * 8];
        sacc[ntl] = __builtin_amdgcn_mfma_f32_16x16x32_bf16(af, qreg[st], sacc[ntl], 0, 0, 0);
      }
    }
    __builtin_amdgcn_s_setprio(0);

    // ---- mask byte for this lane: bit (ntl*4+r) = alive(key kh*32+ntl*16+4g+r)
    uint mybits = (pmlds[(kt << 1) + kh] >> (g << 3)) & 0xffu;

    // ---- in-lane online softmax for q-row l15 (8 key-values in regs)
    float v[8];
    #pragma unroll
    for (int ntl = 0; ntl < 2; ++ntl)
      #pragma unroll
      for (int r = 0; r < 4; ++r)
        v[ntl * 4 + r] = (mybits & (1u << (ntl * 4 + r))) ? sacc[ntl][r] : -1e30f;
    float tm = fmaxf(fmaxf(fmaxf(v[0], v[1]), fmaxf(v[2], v[3])),
                     fmaxf(fmaxf(v[4], v[5]), fmaxf(v[6], v[7])));
    tm = fmaxf(tm, __shfl_xor(tm, 16));
    tm = fmaxf(tm, __shfl_xor(tm, 32));
    float mo = m_s;
    float mn = fmaxf(mo, tm);
    float p[8];
    #pragma unroll
    for (int j = 0; j < 8; ++j) p[j] = __expf(v[j] - mn);  // masked -> exp(-1e30)=0
    float rs = ((p[0] + p[1]) + (p[2] + p[3])) + ((p[4] + p[5]) + (p[6] + p[7]));
    rs += __shfl_xor(rs, 16);
    rs += __shfl_xor(rs, 32);
    if (__any((int)(mn > mo))) {
      float sc = __expf(mo - mn);
      m_s = mn;
      l_s = l_s * sc + rs;
      #pragma unroll
      for (int nt = 0; nt < 16; ++nt) acc_o[nt] *= sc;
    } else {
      l_s += rs;
    }

    // ---- P^T to LDS: ps[q=l15][key ntl*16+4g+r] ; 2x ds_write_b64
    #pragma unroll
    for (int ntl = 0; ntl < 2; ++ntl) {
      uint2 pk;
      pk.x = (uint)f2bf(p[ntl*4+0]) | ((uint)f2bf(p[ntl*4+1]) << 16);
      pk.y = (uint)f2bf(p[ntl*4+2]) | ((uint)f2bf(p[ntl*4+3]) << 16);
      *(uint2*)&psw[l15 * 40 + ntl * 16 + 4 * g] = pk;
    }

    // ---- PV (swapped): O^T[d][q] += V^T[d][k] @ P^T[k][q], K=32 (our half)
    bf16x8 pa = *(const bf16x8*)&psw[l15 * 40 + (g << 3)];   // B-frag: col=q, keys 8g..
    const int kc = (kh << 2) + g;
    __builtin_amdgcn_s_setprio(1);
    #pragma unroll
    for (int nt = 0; nt < 16; ++nt) {
      bf16x8 vf = *(const bf16x8*)&vt_[((kc << 8) + ((nt * 16 + l15) ^ ((kc & 3) << 1))) * 8];
      acc_o[nt] = __builtin_amdgcn_mfma_f32_16x16x32_bf16(vf, pa, acc_o[nt], 0, 0, 0);
    }
    __builtin_amdgcn_s_setprio(0);

    asm volatile("s_waitcnt vmcnt(0)" ::: "memory");
    __syncthreads();
  };

  for (int kt2 = 0; kt2 < NTILES; kt2 += 2) {
    tile_body(kt2,     vs0, vt0, vs1, vt1);
    tile_body(kt2 + 1, vs1, vt1, vs0, vt0);
  }

  // ---- flash-merge across the kh pair (reuse vs/vt LDS region)
  f32x4* accS = (f32x4*)(smem + 1024);              // 4 pq x 64 lanes x 16 = 64KB
  float*  mlS = (float*)(smem + 1024 + 65536);      // 4 pq x 64 lanes x 2 = 2KB
  if (kh) {
    #pragma unroll
    for (int nt = 0; nt < 16; ++nt)
      accS[((pq << 6) + lane) * 16 + nt] = acc_o[nt];
    mlS[((pq << 6) + lane) * 2]     = m_s;
    mlS[((pq << 6) + lane) * 2 + 1] = l_s;
  }
  __syncthreads();
  if (!kh) {
    float mB = mlS[((pq << 6) + lane) * 2];
    float lB = mlS[((pq << 6) + lane) * 2 + 1];
    float m  = fmaxf(m_s, mB);
    float eA = __expf(m_s - m);
    float eB = __expf(mB - m);
    float inv = 1.f / (l_s * eA + lB * eB);
    float fA = eA * inv;
    float fB = eB * inv;
    const size_t obase = (size_t)(qrow0 + (pq << 4) + l15) * DIMC + 4 * g;
    #pragma unroll
    for (int nt = 0; nt < 16; ++nt) {
      f32x4 oB = accS[((pq << 6) + lane) * 16 + nt];
      f32x4 o = acc_o[nt] * fA + oB * fB;
      *(float4*)&out[obase + nt * 16] = *(float4*)&o;
    }
  }
}

extern "C" void kernel_launch(void* const* d_in, const int* in_sizes, int n_in,
                              void* d_out, int out_size, void* d_ws, size_t ws_size,
                              hipStream_t stream) {
  const float* x    = (const float*)d_in[0];
  const float* W    = (const float*)d_in[1];
  const float* bias = (const float*)d_in[2];
  const int*   mask = (const int*)d_in[3];
  float* out = (float*)d_out;

  const size_t n = (size_t)NB * NS * DIMC;      // 4.19M elements
  ushort* qb  = (ushort*)d_ws;                  // 8.4 MB
  ushort* vb  = qb + n;                         // 8.4 MB
  ushort* vtb = vb + n;                         // 8.4 MB
  uint* pm32 = (uint*)(vtb + n);                // 2 KB
  float* Wt = (float*)(pm32 + 512);             // 512 KB

  wtrans_kernel<<<512, 256, 0, stream>>>(W, Wt);
  mask_pack_kernel<<<8, 64, 0, stream>>>(mask, pm32);
  qv_proj_kernel<<<(NB * NS) / 16, 256, 0, stream>>>(x, Wt, bias, qb, vb, vtb);

  const int smem_bytes = 1024 + 4 * VS_ELEMS * 2 + 8 * 16 * 40 * 2;  // ~142 KB
  attn_kernel<<<(NB * NS) / 64, 512, smem_bytes, stream>>>(qb, vb, vtb, pm32, out);
}

// Round 5
// 174.608 us; speedup vs baseline: 2.1620x; 1.1840x over previous
//
#include <hip/hip_runtime.h>
#include <hip/hip_bf16.h>

#define DIMC 256
#define NB 4
#define NS 4096
#define KT 64               // keys per tile in attention
#define NTILES (NS / KT)
#define VS_ELEMS (KT * DIMC)   // 16384 ushorts per 32KB tile buffer

typedef __attribute__((ext_vector_type(4))) float f32x4;
typedef __attribute__((ext_vector_type(8))) short bf16x8;

__device__ __forceinline__ ushort f2bf(float f) {
  __hip_bfloat16 h = __float2bfloat16(f);
  return *reinterpret_cast<ushort*>(&h);
}
__device__ __forceinline__ float bf2f(ushort h) {
  uint u = ((uint)h) << 16;
  float f;
  __builtin_memcpy(&f, &u, 4);
  return f;
}

// async global->LDS DMA, 16B per lane; LDS dest = wave-uniform base + lane*16
__device__ __forceinline__ void gload16(const ushort* g, ushort* l) {
  __builtin_amdgcn_global_load_lds(
      (const __attribute__((address_space(1))) unsigned int*)g,
      (__attribute__((address_space(3))) unsigned int*)l,
      16, 0, 0);
}

// ---------------- W split (once): Whl[2][512][256] bf16 hi/lo ----------------
// col in [0,256): q output col (W row col); col in [256,512): v col (W row col+256)
__global__ void wsplit_kernel(const float* __restrict__ W, ushort* __restrict__ Whl) {
  const int col = blockIdx.x;          // 0..511
  const int k = threadIdx.x;           // 0..255
  const int srcrow = (col < 256) ? col : (col + 256);
  float f = W[(size_t)srcrow * 256 + k];
  ushort h = f2bf(f);
  Whl[(size_t)col * 256 + k] = h;
  Whl[131072 + (size_t)col * 256 + k] = f2bf(f - bf2f(h));
}

// ---------------- QV projection via MFMA (3-term bf16 compensation) ----------
// Block: 64 x-rows x 512 cols; 4 waves, wave w owns all 64 rows x 128 cols.
// qb = (x @ Wq^T + bq)/16 bf16 [B*S][256];  vb = x @ Wv^T + bv bf16 [B*S][256]
// vtb = v transposed per batch [B][256][S] bf16
__global__ __launch_bounds__(256) void qv_proj_kernel(
    const float* __restrict__ x, const ushort* __restrict__ Whl,
    const float* __restrict__ bias,
    ushort* __restrict__ qb, ushort* __restrict__ vb, ushort* __restrict__ vtb)
{
  const int tid  = threadIdx.x;
  const int w    = tid >> 6;
  const int lane = tid & 63;
  const int l15  = lane & 15;
  const int g    = (lane >> 4) & 3;
  const int r0   = blockIdx.x << 6;    // 64 rows
  const int colbase = w << 7;          // 128 cols per wave

  __shared__ ushort olds[64 * 520];    // output transpose staging (65KB)

  f32x4 acc[4][8];
  #pragma unroll
  for (int rt = 0; rt < 4; ++rt)
    #pragma unroll
    for (int ct = 0; ct < 8; ++ct) { acc[rt][ct].x=0.f; acc[rt][ct].y=0.f; acc[rt][ct].z=0.f; acc[rt][ct].w=0.f; }

  #pragma unroll 1
  for (int st = 0; st < 8; ++st) {
    // x A-frags: rows rt*16+l15, k = st*32 + g*8 .. +8 ; split to hi/lo bf16
    bf16x8 xh[4], xl[4];
    #pragma unroll
    for (int rt = 0; rt < 4; ++rt) {
      const float* p = x + (size_t)(r0 + rt * 16 + l15) * DIMC + st * 32 + g * 8;
      float4 f0 = *(const float4*)p;
      float4 f1 = *(const float4*)(p + 4);
      union { bf16x8 v; ushort u[8]; } uh, ul;
      #pragma unroll
      for (int e = 0; e < 8; ++e) {
        float fe = (e < 4) ? ((const float*)&f0)[e] : ((const float*)&f1)[e - 4];
        ushort h = f2bf(fe);
        uh.u[e] = h;
        ul.u[e] = f2bf(fe - bf2f(h));
      }
      xh[rt] = uh.v;
      xl[rt] = ul.v;
    }
    // W B-frags straight from L2; 3-term accumulate
    #pragma unroll
    for (int ct = 0; ct < 8; ++ct) {
      const ushort* wp = Whl + (size_t)(colbase + ct * 16 + l15) * 256 + st * 32 + g * 8;
      bf16x8 wh = *(const bf16x8*)wp;
      bf16x8 wl = *(const bf16x8*)(wp + 131072);
      #pragma unroll
      for (int rt = 0; rt < 4; ++rt) {
        acc[rt][ct] = __builtin_amdgcn_mfma_f32_16x16x32_bf16(xh[rt], wh, acc[rt][ct], 0, 0, 0);
        acc[rt][ct] = __builtin_amdgcn_mfma_f32_16x16x32_bf16(xl[rt], wh, acc[rt][ct], 0, 0, 0);
        acc[rt][ct] = __builtin_amdgcn_mfma_f32_16x16x32_bf16(xh[rt], wl, acc[rt][ct], 0, 0, 0);
      }
    }
  }

  // epilogue: bias (+ q scale), bf16, LDS transpose staging
  // D-map (verified): out-row = rt*16 + 4g + r, out-col = ct*16 + l15
  const float qscale = (colbase < 256) ? 0.0625f : 1.0f;
  #pragma unroll
  for (int ct = 0; ct < 8; ++ct) {
    const int col = colbase + ct * 16 + l15;
    const float bv = bias[(col < 256) ? col : (col + 256)];
    #pragma unroll
    for (int rt = 0; rt < 4; ++rt) {
      #pragma unroll
      for (int r = 0; r < 4; ++r)
        olds[(rt * 16 + 4 * g + r) * 520 + col] = f2bf((acc[rt][ct][r] + bv) * qscale);
    }
  }
  __syncthreads();

  // qb / vb coalesced stores
  #pragma unroll
  for (int i = 0; i < 16; ++i) {
    int task = tid + i * 256;          // 0..4095
    int row = task >> 6, ch = task & 63;
    uint4 d = *(const uint4*)&olds[row * 520 + ch * 8];
    if (ch < 32) *(uint4*)&qb[(size_t)(r0 + row) * DIMC + ch * 8] = d;
    else         *(uint4*)&vb[(size_t)(r0 + row) * DIMC + (ch - 32) * 8] = d;
  }
  // vtb stores: vtb[b][vcol][s]
  const int bbp = r0 >> 12;
  const int s0  = r0 & (NS - 1);
  const int vcol = tid;                // 0..255
  #pragma unroll
  for (int o = 0; o < 8; ++o) {
    union { uint4 v; ushort u[8]; } pk;
    #pragma unroll
    for (int j = 0; j < 8; ++j)
      pk.u[j] = olds[(o * 8 + j) * 520 + 256 + vcol];
    *(uint4*)&vtb[((size_t)(bbp * DIMC + vcol)) * NS + s0 + o * 8] = pk.v;
  }
}

// ---------------- mask -> packed words ----------------
// pm32[b][kt][kh]: bit (8g + ntl*4 + r) = mask[b][kt*64 + kh*32 + ntl*16 + 4g + r]
__global__ void mask_pack_kernel(const int* __restrict__ mask, uint* __restrict__ pm32) {
  int t = blockIdx.x * 64 + threadIdx.x;   // 512 threads total
  int b = t >> 7;
  int kt = (t >> 1) & 63;
  int kh = t & 1;
  const int* mrow = mask + b * NS + kt * 64 + kh * 32;
  uint wd = 0;
  for (int g = 0; g < 4; ++g)
    for (int ntl = 0; ntl < 2; ++ntl)
      for (int r = 0; r < 4; ++r)
        if (mrow[ntl * 16 + 4 * g + r] != 0) wd |= 1u << (8 * g + ntl * 4 + r);
  pm32[t] = wd;
}

// ---------------- flash attention (q @ v^T softmax @ v) ----------------
// 8 waves/block: wave = (pq = w>>1 q-tile, kh = w&1 key-half).
// Swapped MFMAs: QK^T computes S^T (lane owns one q-row -> in-lane softmax),
// PV computes O^T = V^T @ P^T. Per-wave online-softmax state is scalar.
__global__ __launch_bounds__(512, 2) void attn_kernel(
    const ushort* __restrict__ qb, const ushort* __restrict__ vb,
    const ushort* __restrict__ vtb, const uint* __restrict__ pm32,
    float* __restrict__ out)
{
  const int tid  = threadIdx.x;
  const int w    = tid >> 6;
  const int lane = tid & 63;
  const int l15  = lane & 15;
  const int g    = (lane >> 4) & 3;
  const int kh   = w & 1;        // key half
  const int pq   = w >> 1;       // q-tile index

  const int qrow0 = blockIdx.x << 6;   // 64 q rows per block
  const int bb    = qrow0 >> 12;

  extern __shared__ __align__(16) char smem[];
  uint*   pmlds = (uint*)smem;                        // 512 B
  ushort* vs0  = (ushort*)(smem + 1024);              // 32KB key-major V (swizzled)
  ushort* vs1  = vs0 + VS_ELEMS;                      // 32KB
  ushort* vt0  = vs1 + VS_ELEMS;                      // 32KB V^T 8-key chunks (swizzled)
  ushort* vt1  = vt0 + VS_ELEMS;                      // 32KB
  ushort* psb  = vt1 + VS_ELEMS;                      // 8 waves x 16 x 40 = 10KB

  // ---- Q into registers (B-frag role: lane l15 = q-col, chunk (st*4+g))
  const int qrow = qrow0 + (pq << 4) + l15;
  bf16x8 qreg[8];
  #pragma unroll
  for (int st = 0; st < 8; ++st)
    qreg[st] = *(const bf16x8*)&qb[(size_t)qrow * DIMC + ((st * 4 + g) << 3)];

  if (tid < 128) pmlds[tid] = pm32[(bb << 7) + tid];

  // ---- staging helper (8 waves cooperate)
  auto stage = [&](int kt, ushort* vsN, ushort* vtN) {
    const ushort* vbase = vb + ((size_t)(bb * NS + kt * KT)) * DIMC;
    #pragma unroll
    for (int i = 0; i < 4; ++i) {
      int rr0 = (w << 3) + (i << 1);
      int row = rr0 + (lane >> 5);
      int cs  = lane & 31;
      gload16(vbase + row * DIMC + ((cs ^ (row & 7)) << 3), vsN + (rr0 << 8));
    }
    #pragma unroll
    for (int i = 0; i < 4; ++i) {
      int d0 = i << 6;
      int dim = (d0 + lane) ^ ((w & 3) << 1);
      gload16(vtb + ((size_t)(bb * DIMC + dim)) * NS + kt * KT + (w << 3),
              vtN + ((w << 8) + d0) * 8);
    }
  };

  stage(0, vs0, vt0);
  asm volatile("s_waitcnt vmcnt(0)" ::: "memory");
  __syncthreads();

  f32x4 acc_o[16];
  #pragma unroll
  for (int nt = 0; nt < 16; ++nt) { acc_o[nt].x=0.f; acc_o[nt].y=0.f; acc_o[nt].z=0.f; acc_o[nt].w=0.f; }
  float m_s = -30.f;   // scores are O(10) max; -30 floor makes exp(masked-m)==0 exact
  float l_s = 0.f;

  ushort* psw = psb + w * (16 * 40);

  auto tile_body = [&](int kt, const ushort* vs_, const ushort* vt_,
                       ushort* vsN, ushort* vtN) {
    if (kt + 1 < NTILES) stage(kt + 1, vsN, vtN);

    // ---- QK^T (swapped): S^T[key 4g+r + 16ntl][q l15] for our kh half
    f32x4 sacc[2];
    sacc[0].x=0.f; sacc[0].y=0.f; sacc[0].z=0.f; sacc[0].w=0.f;
    sacc[1] = sacc[0];
    __builtin_amdgcn_s_setprio(1);
    #pragma unroll
    for (int st = 0; st < 8; ++st) {
      #pragma unroll
      for (int ntl = 0; ntl < 2; ++ntl) {
        int key = ((kh << 1) + ntl) * 16 + l15;   // A-frag row = key
        bf16x8 af = *(const bf16x8*)&vs_[(key * 32 + ((st * 4 + g) ^ (key & 7))) * 8];
        sacc[ntl] = __builtin_amdgcn_mfma_f32_16x16x32_bf16(af, qreg[st], sacc[ntl], 0, 0, 0);
      }
    }
    __builtin_amdgcn_s_setprio(0);

    // ---- mask byte for this lane: bit (ntl*4+r) = alive(key kh*32+ntl*16+4g+r)
    uint mybits = (pmlds[(kt << 1) + kh] >> (g << 3)) & 0xffu;

    // ---- in-lane online softmax for q-row l15 (8 key-values in regs)
    float v[8];
    #pragma unroll
    for (int ntl = 0; ntl < 2; ++ntl)
      #pragma unroll
      for (int r = 0; r < 4; ++r)
        v[ntl * 4 + r] = (mybits & (1u << (ntl * 4 + r))) ? sacc[ntl][r] : -1e30f;
    float tm = fmaxf(fmaxf(fmaxf(v[0], v[1]), fmaxf(v[2], v[3])),
                     fmaxf(fmaxf(v[4], v[5]), fmaxf(v[6], v[7])));
    tm = fmaxf(tm, __shfl_xor(tm, 16));
    tm = fmaxf(tm, __shfl_xor(tm, 32));
    float mo = m_s;
    float mn = fmaxf(mo, tm);
    float p[8];
    #pragma unroll
    for (int j = 0; j < 8; ++j) p[j] = __expf(v[j] - mn);  // masked -> exp(-1e30)=0
    float rs = ((p[0] + p[1]) + (p[2] + p[3])) + ((p[4] + p[5]) + (p[6] + p[7]));
    rs += __shfl_xor(rs, 16);
    rs += __shfl_xor(rs, 32);
    if (__any((int)(mn > mo))) {
      float sc = __expf(mo - mn);
      m_s = mn;
      l_s = l_s * sc + rs;
      #pragma unroll
      for (int nt = 0; nt < 16; ++nt) acc_o[nt] *= sc;
    } else {
      l_s += rs;
    }

    // ---- P^T to LDS: ps[q=l15][key ntl*16+4g+r] ; 2x ds_write_b64
    #pragma unroll
    for (int ntl = 0; ntl < 2; ++ntl) {
      uint2 pk;
      pk.x = (uint)f2bf(p[ntl*4+0]) | ((uint)f2bf(p[ntl*4+1]) << 16);
      pk.y = (uint)f2bf(p[ntl*4+2]) | ((uint)f2bf(p[ntl*4+3]) << 16);
      *(uint2*)&psw[l15 * 40 + ntl * 16 + 4 * g] = pk;
    }

    // ---- PV (swapped): O^T[d][q] += V^T[d][k] @ P^T[k][q], K=32 (our half)
    bf16x8 pa = *(const bf16x8*)&psw[l15 * 40 + (g << 3)];   // B-frag: col=q, keys 8g..
    const int kc = (kh << 2) + g;
    __builtin_amdgcn_s_setprio(1);
    #pragma unroll
    for (int nt = 0; nt < 16; ++nt) {
      bf16x8 vf = *(const bf16x8*)&vt_[((kc << 8) + ((nt * 16 + l15) ^ ((kc & 3) << 1))) * 8];
      acc_o[nt] = __builtin_amdgcn_mfma_f32_16x16x32_bf16(vf, pa, acc_o[nt], 0, 0, 0);
    }
    __builtin_amdgcn_s_setprio(0);

    asm volatile("s_waitcnt vmcnt(0)" ::: "memory");
    __syncthreads();
  };

  for (int kt2 = 0; kt2 < NTILES; kt2 += 2) {
    tile_body(kt2,     vs0, vt0, vs1, vt1);
    tile_body(kt2 + 1, vs1, vt1, vs0, vt0);
  }

  // ---- flash-merge across the kh pair (reuse vs/vt LDS region)
  f32x4* accS = (f32x4*)(smem + 1024);              // 4 pq x 64 lanes x 16 = 64KB
  float*  mlS = (float*)(smem + 1024 + 65536);      // 4 pq x 64 lanes x 2 = 2KB
  if (kh) {
    #pragma unroll
    for (int nt = 0; nt < 16; ++nt)
      accS[((pq << 6) + lane) * 16 + nt] = acc_o[nt];
    mlS[((pq << 6) + lane) * 2]     = m_s;
    mlS[((pq << 6) + lane) * 2 + 1] = l_s;
  }
  __syncthreads();
  if (!kh) {
    float mB = mlS[((pq << 6) + lane) * 2];
    float lB = mlS[((pq << 6) + lane) * 2 + 1];
    float m  = fmaxf(m_s, mB);
    float eA = __expf(m_s - m);
    float eB = __expf(mB - m);
    float inv = 1.f / (l_s * eA + lB * eB);
    float fA = eA * inv;
    float fB = eB * inv;
    const size_t obase = (size_t)(qrow0 + (pq << 4) + l15) * DIMC + 4 * g;
    #pragma unroll
    for (int nt = 0; nt < 16; ++nt) {
      f32x4 oB = accS[((pq << 6) + lane) * 16 + nt];
      f32x4 o = acc_o[nt] * fA + oB * fB;
      *(float4*)&out[obase + nt * 16] = *(float4*)&o;
    }
  }
}

extern "C" void kernel_launch(void* const* d_in, const int* in_sizes, int n_in,
                              void* d_out, int out_size, void* d_ws, size_t ws_size,
                              hipStream_t stream) {
  const float* x    = (const float*)d_in[0];
  const float* W    = (const float*)d_in[1];
  const float* bias = (const float*)d_in[2];
  const int*   mask = (const int*)d_in[3];
  float* out = (float*)d_out;

  const size_t n = (size_t)NB * NS * DIMC;      // 4.19M elements
  ushort* qb  = (ushort*)d_ws;                  // 8.4 MB
  ushort* vb  = qb + n;                         // 8.4 MB
  ushort* vtb = vb + n;                         // 8.4 MB
  uint* pm32 = (uint*)(vtb + n);                // 2 KB
  ushort* Whl = (ushort*)(pm32 + 512);          // 512 KB

  wsplit_kernel<<<512, 256, 0, stream>>>(W, Whl);
  mask_pack_kernel<<<8, 64, 0, stream>>>(mask, pm32);
  qv_proj_kernel<<<(NB * NS) / 64, 256, 0, stream>>>(x, Whl, bias, qb, vb, vtb);

  const int smem_bytes = 1024 + 4 * VS_ELEMS * 2 + 8 * 16 * 40 * 2;  // ~142 KB
  attn_kernel<<<(NB * NS) / 64, 512, smem_bytes, stream>>>(qb, vb, vtb, pm32, out);
}